// Round 9
// baseline (120.873 us; speedup 1.0000x reference)
//
#include <hip/hip_runtime.h>
#include <math.h>

#define NQ 12
#define NL 6
#define BATCHN 8192
#define DIN 512

typedef _Float16 f16;
typedef __attribute__((ext_vector_type(8)))  _Float16 f16x8;
typedef __attribute__((ext_vector_type(16))) float    f32x16;
typedef unsigned int u32;
typedef __attribute__((ext_vector_type(4))) u32 u32x4;
typedef __attribute__((ext_vector_type(2))) int i32x2;

// ============================================================================
// 10-matmul formulation. State = 64x64 (P: wires 0-5, Q: wires 6-11). MFMA
// contracts the reg-resident factor and swaps residency; CNOT chain folded
// into matrices (F6 prefix-xor) / repack (dpp+bfi) / measurement algebra.
// Evidence ledger:
//  R16: LDS-staged B -> per-block latency 13.9->10.7us (load latency IS the
//    stall); LDS residency cap -> net loss.
//  R18 (current best, 51.0us): global_load_lds 2x8KiB double-buffer,
//    per-step vmcnt(0)+barrier. VGPR 68 arch + 64 acc = 132 total.
//  R19: 1-wave zero-barrier: per-wave 13.2->11.7us but residency fell -> 63us.
//  R20: waves_per_eu(4,8) squeeze to 64 arch: occupancy 26->31.6% but 2.3MB
//    spill -> per-wave 13.2->16.3us -> dur unchanged. Lesson: allocator
//    squeeze spills; need STRUCTURAL shave below 64 arch with slack. Also at
//    exactly 128 total the residency was 2.5 not 4 (boundary exclusive or
//    scratch-capped) -> target total ~116-120.
// R21: half of fr staging (kt=2,3: 16 regs) moved to LDS. Repack writes
//   ds_write_b128 at lane*16B (same pattern as B reads; measured 0 bank
//   conflicts); MFMA loop reads them back ~250cy later (covered by kt=0,1
//   MFMAs). Arch ~52-56, total ~116-120, no spill expected. LDS 32KiB/block
//   (5 blocks/CU cap, not binding). R18 pipeline otherwise unchanged.
// ============================================================================

__device__ __forceinline__ u32 pkrtz(float a, float b) {
  auto p = __builtin_amdgcn_cvt_pkrtz(a, b);   // __fp16 ext_vector(2)
  return __builtin_bit_cast(u32, p);
}
__device__ __forceinline__ u32 bperm(int addr, u32 v) {
  return (u32)__builtin_amdgcn_ds_bpermute(addr, (int)v);
}
__device__ __forceinline__ float dppx1(float v) {  // lane xor 1 (quad_perm)
  return __int_as_float(__builtin_amdgcn_mov_dpp(__float_as_int(v), 0xB1, 0xF, 0xF, true));
}
__device__ __forceinline__ u32 dppx1u(u32 v) {
  return (u32)__builtin_amdgcn_mov_dpp((int)v, 0xB1, 0xF, 0xF, true);
}
__device__ __forceinline__ float dppx2(float v) {
  return __int_as_float(__builtin_amdgcn_mov_dpp(__float_as_int(v), 0x4E, 0xF, 0xF, true));
}
__device__ __forceinline__ float dppx8(float v) {  // row_ror:8 == xor 8
  return __int_as_float(__builtin_amdgcn_mov_dpp(__float_as_int(v), 0x128, 0xF, 0xF, true));
}
template <int PAT>
__device__ __forceinline__ float swzf(float v) {
  return __int_as_float(__builtin_amdgcn_ds_swizzle(__float_as_int(v), PAT));
}

// half-swap across the lane-32 boundary.
#if __has_builtin(__builtin_amdgcn_permlane32_swap)
__device__ __forceinline__ void pswap(u32& a, u32& b) {
  i32x2 r = __builtin_amdgcn_permlane32_swap((int)a, (int)b, false, false);
  a = (u32)r.x; b = (u32)r.y;
}
#else
#define PSWAP_FALLBACK 1
__device__ __forceinline__ void pswap_fb(u32& a, u32& b, bool hi, int axor) {
  u32 xa = bperm(axor, a), xb = bperm(axor, b);
  u32 na = hi ? xb : a;
  u32 nb = hi ? b : xa;
  a = na; b = nb;
}
#endif

__device__ __forceinline__ float wave_sum(float v) {
  v += dppx1(v);
  v += dppx2(v);
  v += swzf<0x101F>(v);   // xor 4
  v += dppx8(v);
  v += swzf<0x401F>(v);   // xor 16
#ifndef PSWAP_FALLBACK
  // cross-32 stage via permlane32_swap: a+b == row0sum + row1sum in every lane
  u32 a = __builtin_bit_cast(u32, v), b = a;
  pswap(a, b);
  return __builtin_bit_cast(float, a) + __builtin_bit_cast(float, b);
#else
  return v + __shfl_xor(v, 32, 64);
#endif
}
__device__ __forceinline__ f16x8 asf(const u32 a[4]) {
  u32x4 v; v.x = a[0]; v.y = a[1]; v.z = a[2]; v.w = a[3];
  return __builtin_bit_cast(f16x8, v);
}
__device__ __forceinline__ f16x8 ldB(const u32* __restrict__ p, int off) {
  u32x4 v = *(const u32x4*)(p + off);
  return __builtin_bit_cast(f16x8, v);
}
__device__ __forceinline__ f16x8 ldL(const u32* p, int off) {   // LDS load
  u32x4 v = *(const u32x4*)(p + off);
  return __builtin_bit_cast(f16x8, v);
}

// ---- async global->LDS staging of one 8KiB matrix (2 chunks per wave,
// 4 waves cover 8 chunks). No destination registers consumed.
#if __has_builtin(__builtin_amdgcn_global_load_lds)
#define HAVE_GLLDS 1
__device__ __forceinline__ void stage_mat(const u32* __restrict__ Bg,
                                          u32* lbuf, int wid, int lane) {
  #pragma unroll
  for (int c2 = 0; c2 < 2; ++c2) {
    const int c = wid * 2 + c2;
    const u32* g = Bg + c * 256 + lane * 4;
    u32* l = lbuf + c * 256;
    __builtin_amdgcn_global_load_lds(
        (const __attribute__((address_space(1))) u32*)g,
        (__attribute__((address_space(3))) u32*)l, 16, 0, 0);
  }
}
#else
__device__ __forceinline__ void stage_mat(const u32* __restrict__ Bg,
                                          u32* lbuf, int wid, int lane) {
  #pragma unroll
  for (int c2 = 0; c2 < 2; ++c2) {
    const int c = wid * 2 + c2;
    u32x4 v = *(const u32x4*)(Bg + c * 256 + lane * 4);
    *(u32x4*)(lbuf + c * 256 + lane * 4) = v;
  }
}
#endif

// fast sin/cos in revolutions (v_sin_f32/v_cos_f32 after fract reduction)
__device__ __forceinline__ void sincos_rev(float rev, float* s, float* c) {
  float r = rev - floorf(rev);
#if __has_builtin(__builtin_amdgcn_sinf) && __has_builtin(__builtin_amdgcn_cosf)
  *s = __builtin_amdgcn_sinf(r);
  *c = __builtin_amdgcn_cosf(r);
#else
  const float TWO_PI = 6.28318530717958647693f;
  sincosf(r * TWO_PI, s, c);
#endif
}

// conditional lane-xor-1 on a packed word (bfi idiom; halves have opposite
// flip conditions).
__device__ __forceinline__ u32 foldw(u32 w, u32 m) {
  u32 partner = dppx1u(w);
  return (m & partner) | (~m & w);
}

// ---------- setup: matrices (fp16, B-fragment order) from weights -----------
__global__ void setup_mats(const float* __restrict__ weights, u32* __restrict__ Bbuf) {
  const int mm = blockIdx.x >> 3;   // 0..11 ; layer = mm>>1, side: 0=P,1=Q
  const int l  = mm >> 1;
  const int qs = mm & 1;
  __shared__ float c6[6], s6[6];
  if (threadIdx.x < 6) {
    float h = 0.5f * weights[l * NQ + qs * 6 + threadIdx.x];
    c6[threadIdx.x] = cosf(h);
    s6[threadIdx.x] = sinf(h);
  }
  __syncthreads();
  const int t = (blockIdx.x & 7) * 256 + threadIdx.x;   // 0..2047
  const int lane = (t >> 2) & 63;
  const int fk   = t >> 8;          // nt*4 + kt
  const int kt   = fk & 3;
  const int nt   = fk >> 2;
  const int n     = nt * 32 + (lane & 31);
  const int kbase = kt * 16 + (lane >> 5) * 8 + (t & 3) * 2;
  float v[2];
  #pragma unroll
  for (int u = 0; u < 2; ++u) {
    int k = kbase + u;
    int bb = k;
    if (l >= 1) { bb ^= bb << 1; bb ^= bb << 2; bb ^= bb << 4; bb &= 63; } // F6 = prefix-xor
    float prod = 1.f;
    #pragma unroll
    for (int w = 0; w < 6; ++w) {
      const int aw = (n >> w) & 1, bw = (bb >> w) & 1;
      prod *= (aw == bw) ? c6[w] : (aw ? s6[w] : -s6[w]);  // RY: [[c,-s],[s,c]]
    }
    v[u] = prod;
  }
  Bbuf[mm * 2048 + t] = pkrtz(v[0], v[1]);
}

// ---------- one matmul step: repack prev D -> A frags, 16 MFMA --------------
// fr for kt=0,1 stays in regs (16); kt=2,3 goes through LDS (frp, 4KiB/wave;
// ds_write_b128 then ds_read_b128 ~250cy later under kt=0,1's MFMAs).
template <bool FOLD>
__device__ __forceinline__ void mm_step(f32x16 (&d)[2][2],
                                        const u32* Bl, u32* frp,
                                        u32 maskA, u32 maskB) {
  f16x8 Bc0 = ldB(Bl, 0 * 256);
  f16x8 Bc1 = ldB(Bl, 4 * 256);
  u32 fr[2][2][4];
  #pragma unroll
  for (int kt = 0; kt < 4; ++kt) {
    const int s  = kt >> 1;
    const int b0 = 4 * ((2 * kt) & 3);
    const int b1 = 4 * ((2 * kt + 1) & 3);
    #pragma unroll
    for (int mt = 0; mt < 2; ++mt) {
      u32 p0a = pkrtz(d[s][mt][b0 + 0], d[s][mt][b0 + 1]);
      u32 p0b = pkrtz(d[s][mt][b0 + 2], d[s][mt][b0 + 3]);
      u32 p1a = pkrtz(d[s][mt][b1 + 0], d[s][mt][b1 + 1]);
      u32 p1b = pkrtz(d[s][mt][b1 + 2], d[s][mt][b1 + 3]);
      if (FOLD) {
        const int PAR4[4] = {0, 1, 1, 0};
        const int ka = (PAR4[b0 >> 2] + s) & 1;   // low-half class of p0a
        const int kc = (PAR4[b1 >> 2] + s) & 1;   // low-half class of p1a
        p0a = foldw(p0a, ka ? maskB : maskA);
        p0b = foldw(p0b, ka ? maskA : maskB);
        p1a = foldw(p1a, kc ? maskB : maskA);
        p1b = foldw(p1b, kc ? maskA : maskB);
      }
#ifdef PSWAP_FALLBACK
      pswap_fb(p0a, p1a, false, 0);   // unreachable config on gfx950
      pswap_fb(p0b, p1b, false, 0);
#else
      pswap(p0a, p1a);
      pswap(p0b, p1b);
#endif
      if (kt < 2) {
        fr[mt][kt][0] = p0a;
        fr[mt][kt][1] = p0b;
        fr[mt][kt][2] = p1a;
        fr[mt][kt][3] = p1b;
      } else {
        u32x4 v; v.x = p0a; v.y = p0b; v.z = p1a; v.w = p1b;
        *(u32x4*)(frp + ((kt - 2) * 2 + mt) * 256) = v;   // slot*1KiB
      }
    }
  }
  #pragma unroll
  for (int kt = 0; kt < 4; ++kt) {
    f16x8 B0 = Bc0, B1 = Bc1;
    if (kt < 3) {
      Bc0 = ldB(Bl, (kt + 1) * 256);       // issue next pair before MFMAs
      Bc1 = ldB(Bl, (4 + kt + 1) * 256);
    }
    f16x8 A0, A1;
    if (kt < 2) {
      A0 = asf(fr[0][kt]);
      A1 = asf(fr[1][kt]);
    } else {
      A0 = ldL(frp, ((kt - 2) * 2 + 0) * 256);
      A1 = ldL(frp, ((kt - 2) * 2 + 1) * 256);
    }
    if (kt == 0) {
      f32x16 z{};
      d[0][0] = __builtin_amdgcn_mfma_f32_32x32x16_f16(A0, B0, z, 0, 0, 0);
      d[0][1] = __builtin_amdgcn_mfma_f32_32x32x16_f16(A0, B1, z, 0, 0, 0);
      d[1][0] = __builtin_amdgcn_mfma_f32_32x32x16_f16(A1, B0, z, 0, 0, 0);
      d[1][1] = __builtin_amdgcn_mfma_f32_32x32x16_f16(A1, B1, z, 0, 0, 0);
    } else {
      d[0][0] = __builtin_amdgcn_mfma_f32_32x32x16_f16(A0, B0, d[0][0], 0, 0, 0);
      d[0][1] = __builtin_amdgcn_mfma_f32_32x32x16_f16(A0, B1, d[0][1], 0, 0, 0);
      d[1][0] = __builtin_amdgcn_mfma_f32_32x32x16_f16(A1, B0, d[1][0], 0, 0, 0);
      d[1][1] = __builtin_amdgcn_mfma_f32_32x32x16_f16(A1, B1, d[1][1], 0, 0, 0);
    }
  }
}

__global__ void __launch_bounds__(256) __attribute__((amdgpu_waves_per_eu(4, 8)))
dqc_main(const float* __restrict__ x,
         const float* __restrict__ pre_w,
         const float* __restrict__ pre_b,
         const float* __restrict__ weights,
         const float* __restrict__ post_w,
         const float* __restrict__ post_b,
         const u32* __restrict__ Bbuf,
         float* __restrict__ out)
{
  const int lane = threadIdx.x & 63;
  const int wid  = threadIdx.x >> 6;
  const bool hi  = lane >= 32;
  const int b    = blockIdx.x * 4 + wid;
  // flip-partner masks: class k flips lower f16 when k ^ hi == 1.
  const u32 maskA = hi ? 0x0000FFFFu : 0xFFFF0000u;   // parity-class 0
  const u32 maskB = ~maskA;                            // parity-class 1

  // ---- LDS: double-buffered B staging (2 x 8 KiB) + fr spill area
  // (4 waves x 4 KiB). 32 KiB total.
  __shared__ __align__(16) u32 Bs[2][2048];
  __shared__ __align__(16) u32 Fs[4][1024];
  stage_mat(Bbuf + 2 * 2048, &Bs[0][0], wid, lane);   // mm2 -> buf0
  stage_mat(Bbuf + 3 * 2048, &Bs[1][0], wid, lane);   // mm3 -> buf1

  // ---- pre-GEMM: pre[w] = x[b,:] . pre_w[w,:]  (covers staging latency)
  float acc[NQ];
  const float* xr = x + (size_t)b * DIN + lane * 8;
  const float4 xa = *(const float4*)(xr);
  const float4 xb = *(const float4*)(xr + 4);
  #pragma unroll
  for (int w = 0; w < NQ; ++w) {
    const float* wr = pre_w + w * DIN + lane * 8;
    const float4 wa = *(const float4*)(wr);
    const float4 wb = *(const float4*)(wr + 4);
    acc[w] = xa.x * wa.x + xa.y * wa.y + xa.z * wa.z + xa.w * wa.w
           + xb.x * wb.x + xb.y * wb.y + xb.z * wb.z + xb.w * wb.w;
  }
  #pragma unroll
  for (int w = 0; w < NQ; ++w) acc[w] = wave_sum(acc[w]);

  // ---- u0 = cos(theta), u1 = sin(theta),
  // theta = (acc+pre_b)*pi/4 + pi/4 + 0.5*weights[0][w]  (layer-0 folded).
  const float INV_4PI = 0.07957747154594766788f;
  float u0[NQ], u1[NQ];
  #pragma unroll
  for (int w = 0; w < NQ; ++w) {
    const float cw2 = 0.125f + pre_b[w] * 0.125f + weights[w] * INV_4PI;
    const float rev = fmaf(acc[w], 0.125f, cw2);
    sincos_rev(rev, &u1[w], &u0[w]);
  }

  // ---- build MM2's A-frags directly, with layer-0's cond-flip applied:
  // element(m=q, k=p) = P(p) * Q(q ^ (par(p) & 1 on wire6)).
  float base8[8];   // wires 0-2 (j bits)
  #pragma unroll
  for (int j = 0; j < 8; ++j)
    base8[j] = ((j & 1) ? u1[0] : u0[0]) * ((j & 2) ? u1[1] : u0[1]) * ((j & 4) ? u1[2] : u0[2]);
  float hiP[4];     // wires 3(hi),4,5(kt bits)
  #pragma unroll
  for (int kt = 0; kt < 4; ++kt)
    hiP[kt] = (hi ? u1[3] : u0[3]) * ((kt & 1) ? u1[4] : u0[4]) * ((kt & 2) ? u1[5] : u0[5]);
  const float q5 = ((lane & 2) ? u1[7] : u0[7]) * ((lane & 4) ? u1[8] : u0[8])
                 * ((lane & 8) ? u1[9] : u0[9]) * ((lane & 16) ? u1[10] : u0[10]);
  const float qA = q5 * ((lane & 1) ? u1[6] : u0[6]);   // Q(q)
  const float qB = q5 * ((lane & 1) ? u0[6] : u1[6]);   // Q(q ^ wire6)
  const float qeven = hi ? qB : qA;   // class par(p)=0 (hi folded in)
  const float qodd  = hi ? qA : qB;   // class par(p)=1
  const float qe0 = qeven * u0[11], qo0 = qodd * u0[11];   // mt = 0
  const float qe1 = qeven * u1[11], qo1 = qodd * u1[11];   // mt = 1

  // staging complete + visible before first use.
  asm volatile("s_waitcnt vmcnt(0)" ::: "memory");
  __syncthreads();

  const u32* B0p = &Bs[0][0] + lane * 4;
  const u32* B1p = &Bs[1][0] + lane * 4;
  u32* frp = &Fs[wid][0] + lane * 4;

  // ---- s=0: init matmul (mm2) from Bs[0], rolling pair.
  f32x16 d[2][2];
  {
    f16x8 Ic0 = ldB(B0p, 0 * 256);
    f16x8 Ic1 = ldB(B0p, 4 * 256);
    const int PKT[4] = {0, 1, 1, 0};   // parity(kt)
    const int PDW[4] = {0, 1, 1, 0};   // parity(j=2*dw)
    #pragma unroll
    for (int kt = 0; kt < 4; ++kt) {
      u32 a0[4], a1[4];
      #pragma unroll
      for (int dw = 0; dw < 4; ++dw) {
        const float e0 = base8[2 * dw] * hiP[kt];
        const float e1 = base8[2 * dw + 1] * hiP[kt];
        const bool cls = (PKT[kt] ^ PDW[dw]) != 0;   // class of e0 (e1 is ^1)
        a0[dw] = pkrtz((cls ? qo0 : qe0) * e0, (cls ? qe0 : qo0) * e1);
        a1[dw] = pkrtz((cls ? qo1 : qe1) * e0, (cls ? qe1 : qo1) * e1);
      }
      f16x8 B0 = Ic0, B1 = Ic1;
      if (kt < 3) {
        Ic0 = ldB(B0p, (kt + 1) * 256);
        Ic1 = ldB(B0p, (4 + kt + 1) * 256);
      }
      f16x8 A0 = asf(a0), A1 = asf(a1);
      if (kt == 0) {
        f32x16 z{};
        d[0][0] = __builtin_amdgcn_mfma_f32_32x32x16_f16(A0, B0, z, 0, 0, 0);
        d[0][1] = __builtin_amdgcn_mfma_f32_32x32x16_f16(A0, B1, z, 0, 0, 0);
        d[1][0] = __builtin_amdgcn_mfma_f32_32x32x16_f16(A1, B0, z, 0, 0, 0);
        d[1][1] = __builtin_amdgcn_mfma_f32_32x32x16_f16(A1, B1, z, 0, 0, 0);
      } else {
        d[0][0] = __builtin_amdgcn_mfma_f32_32x32x16_f16(A0, B0, d[0][0], 0, 0, 0);
        d[0][1] = __builtin_amdgcn_mfma_f32_32x32x16_f16(A0, B1, d[0][1], 0, 0, 0);
        d[1][0] = __builtin_amdgcn_mfma_f32_32x32x16_f16(A1, B0, d[1][0], 0, 0, 0);
        d[1][1] = __builtin_amdgcn_mfma_f32_32x32x16_f16(A1, B1, d[1][1], 0, 0, 0);
      }
    }
  }

  // ---- step tail: wait prev prefetch, sync, issue prefetch of mat `nextmm`
  // into the buffer just freed by this step.
  #define STEP_TAIL(nextmm, bufidx)                                  \
    do {                                                             \
      asm volatile("s_waitcnt vmcnt(0)" ::: "memory");               \
      __syncthreads();                                               \
      stage_mat(Bbuf + (nextmm) * 2048, &Bs[bufidx][0], wid, lane);  \
    } while (0)

  STEP_TAIL(4, 0);                                   // end s=0: mm4 -> buf0
  mm_step<false>(d, B1p, frp, maskA, maskB);         // s=1: mm3 (buf1)
  STEP_TAIL(5, 1);                                   // mm5 -> buf1
  mm_step<true >(d, B0p, frp, maskA, maskB);         // s=2: mm4 (buf0)
  STEP_TAIL(6, 0);                                   // mm6 -> buf0
  mm_step<false>(d, B1p, frp, maskA, maskB);         // s=3: mm5 (buf1)
  STEP_TAIL(7, 1);                                   // mm7 -> buf1
  mm_step<true >(d, B0p, frp, maskA, maskB);         // s=4: mm6 (buf0)
  STEP_TAIL(8, 0);                                   // mm8 -> buf0
  mm_step<false>(d, B1p, frp, maskA, maskB);         // s=5: mm7 (buf1)
  STEP_TAIL(9, 1);                                   // mm9 -> buf1
  mm_step<true >(d, B0p, frp, maskA, maskB);         // s=6: mm8 (buf0)
  STEP_TAIL(10, 0);                                  // mm10 -> buf0
  mm_step<false>(d, B1p, frp, maskA, maskB);         // s=7: mm9 (buf1)
  STEP_TAIL(11, 1);                                  // mm11 -> buf1
  mm_step<true >(d, B0p, frp, maskA, maskB);         // s=8: mm10 (buf0)
  asm volatile("s_waitcnt vmcnt(0)" ::: "memory");   // mm11 landed
  __syncthreads();
  mm_step<false>(d, B1p, frp, maskA, maskB);         // s=9: mm11 (buf1)
  #undef STEP_TAIL

  // ---- measurement with post_w folded in (wave_sum linearity).
  const float pw0 = post_w[0], pw1 = post_w[1], pw2 = post_w[2],
              pw3 = post_w[3], pw4 = post_w[4], pw5 = post_w[5];
  float A0s = 0.f, A1s = 0.f, s00 = 0.f, s01 = 0.f, accA = 0.f, accB = 0.f;
  #pragma unroll
  for (int mt = 0; mt < 2; ++mt)
    #pragma unroll
    for (int nt = 0; nt < 2; ++nt)
      #pragma unroll
      for (int r = 0; r < 16; ++r) {
        float v = d[mt][nt][r];
        float sq = v * v;
        const int par0 = (__builtin_popcount(r & 3) + __builtin_popcount(r >> 2) + mt) & 1;
        if (par0) A1s += sq; else A0s += sq;
        if (nt == 0) { if (par0) s01 += sq; else s00 += sq; }
        const int c0 = r & 1;
        const int c1 = (r ^ (r >> 1)) & 1;
        const int c3 = c1 ^ ((r >> 2) & 1);
        const int c4 = c3 ^ ((r >> 3) & 1);
        const int c5 = c4 ^ mt;
        const float ca = (c0 ? -pw0 : pw0) + (c1 ? -pw1 : pw1);
        const float cb = (c1 ? -pw2 : pw2) + (c3 ? -pw3 : pw3)
                       + (c4 ? -pw4 : pw4) + (c5 ? -pw5 : pw5);
        accA = fmaf(ca, sq, accA);
        accB = fmaf(cb, sq, accB);
      }
  const float sgnhi = hi ? -1.f : 1.f;
  const float tot   = A0s + A1s;
  const float diff  = sgnhi * (A0s - A1s);
  const float diffs = sgnhi * (2.f * (s00 - s01) - (A0s - A1s));
  float Sq = 0.f;
  #pragma unroll
  for (int j = 0; j < 5; ++j) {
    const int par = __builtin_popcount(lane & ((2 << j) - 1)) & 1;
    Sq += par ? -post_w[6 + j] : post_w[6 + j];
  }
  const float s5 = (__builtin_popcount(lane & 31) & 1) ? -post_w[11] : post_w[11];
  const float zcomb = accA + sgnhi * accB + diff * Sq + diffs * s5;

  const float tots = wave_sum(tot);
  const float zs   = wave_sum(zcomb);

  if (lane == 0) {
    out[b] = fmaf(zs, 1.0f / tots, post_b[0]);
  }
}

extern "C" void kernel_launch(void* const* d_in, const int* in_sizes, int n_in,
                              void* d_out, int out_size, void* d_ws, size_t ws_size,
                              hipStream_t stream) {
  (void)in_sizes; (void)n_in; (void)out_size; (void)ws_size;
  const float* x       = (const float*)d_in[0];
  const float* pre_w   = (const float*)d_in[1];
  const float* pre_b   = (const float*)d_in[2];
  const float* weights = (const float*)d_in[3];
  const float* post_w  = (const float*)d_in[4];
  const float* post_b  = (const float*)d_in[5];
  float* out = (float*)d_out;
  u32* Bbuf = (u32*)d_ws;   // 12 * 2048 dwords = 96 KiB

  setup_mats<<<96, 256, 0, stream>>>(weights, Bbuf);
  dqc_main<<<BATCHN / 4, 256, 0, stream>>>(x, pre_w, pre_b, weights,
                                           post_w, post_b, Bbuf, out);
}

// Round 11
// 115.479 us; speedup vs baseline: 1.0467x; 1.0467x over previous
//
#include <hip/hip_runtime.h>
#include <math.h>

#define NQ 12
#define NL 6
#define BATCHN 8192
#define DIN 512

typedef _Float16 f16;
typedef __attribute__((ext_vector_type(8)))  _Float16 f16x8;
typedef __attribute__((ext_vector_type(16))) float    f32x16;
typedef unsigned int u32;
typedef __attribute__((ext_vector_type(4))) u32 u32x4;
typedef __attribute__((ext_vector_type(2))) int i32x2;

// ============================================================================
// 10-matmul formulation. State = 64x64 (P: wires 0-5, Q: wires 6-11). MFMA
// contracts the reg-resident factor and swaps residency; CNOT chain folded
// into matrices (F6 prefix-xor) / repack (dpp+bfi) / measurement algebra.
// Evidence ledger:
//  R16: LDS-resident B -> per-block 13.9->10.7us (load latency IS the stall).
//  R18 (verified best, 51.0us/dispatch): global_load_lds 2x8KiB dbuf,
//    per-step vmcnt(0)+barrier, 4-wave blocks. VGPR 68+64acc=132 total.
//  R19: zero-barrier 1-wave: per-wave 13.2->11.7us (-11%) but residency
//    8.3->5.9 waves/CU -> net loss. Barriers cost ~11% per-wave.
//  R17/R20/R21: all register diets (squeeze, LDS fr-move) spill 2.3-12MB ->
//    occupancy gains cancelled. 132 total = 2 waves/SIMD is immovable here.
//  R22: split-state (2 waves/element, 32 acc regs) FAILED correctness
//    (absmax 5.8e-2); static re-derivation found no bug -> reverted, not
//    worth more rounds blind.
// R23 = R18 + two safe refinements:
//  (1) 4-buffer rotation (32KiB LDS): stage mm2-5 up front; per 2 steps:
//      barrier -> stage 2 mats into buffers freed 2 steps ago -> 2 steps.
//      Barriers 10 -> 5 (R19 showed barrier cost ~11% per-wave); staging
//      latency cover 1 -> 2 steps. Regs unchanged; 32KiB -> <=5 blocks/CU
//      (regs still bind at ~2 blocks, LDS not binding).
//  (2) s_setprio(1) around MFMA clusters (T5): free; pays when co-resident
//      blocks sit at different phases (2-step barrier spacing adds skew).
// ============================================================================

__device__ __forceinline__ u32 pkrtz(float a, float b) {
  auto p = __builtin_amdgcn_cvt_pkrtz(a, b);   // __fp16 ext_vector(2)
  return __builtin_bit_cast(u32, p);
}
__device__ __forceinline__ float dppx1(float v) {  // lane xor 1 (quad_perm)
  return __int_as_float(__builtin_amdgcn_mov_dpp(__float_as_int(v), 0xB1, 0xF, 0xF, true));
}
__device__ __forceinline__ u32 dppx1u(u32 v) {
  return (u32)__builtin_amdgcn_mov_dpp((int)v, 0xB1, 0xF, 0xF, true);
}
__device__ __forceinline__ float dppx2(float v) {
  return __int_as_float(__builtin_amdgcn_mov_dpp(__float_as_int(v), 0x4E, 0xF, 0xF, true));
}
__device__ __forceinline__ float dppx8(float v) {  // row_ror:8 == xor 8
  return __int_as_float(__builtin_amdgcn_mov_dpp(__float_as_int(v), 0x128, 0xF, 0xF, true));
}
template <int PAT>
__device__ __forceinline__ float swzf(float v) {
  return __int_as_float(__builtin_amdgcn_ds_swizzle(__float_as_int(v), PAT));
}

// half-swap across the lane-32 boundary.
#if __has_builtin(__builtin_amdgcn_permlane32_swap)
__device__ __forceinline__ void pswap(u32& a, u32& b) {
  i32x2 r = __builtin_amdgcn_permlane32_swap((int)a, (int)b, false, false);
  a = (u32)r.x; b = (u32)r.y;
}
#else
#define PSWAP_FALLBACK 1
__device__ __forceinline__ void pswap_fb(u32& a, u32& b, bool hi, int axor) {
  u32 xa = (u32)__builtin_amdgcn_ds_bpermute(axor, (int)a);
  u32 xb = (u32)__builtin_amdgcn_ds_bpermute(axor, (int)b);
  u32 na = hi ? xb : a;
  u32 nb = hi ? b : xa;
  a = na; b = nb;
}
#endif

__device__ __forceinline__ float wave_sum(float v) {
  v += dppx1(v);
  v += dppx2(v);
  v += swzf<0x101F>(v);   // xor 4
  v += dppx8(v);
  v += swzf<0x401F>(v);   // xor 16
#ifndef PSWAP_FALLBACK
  // cross-32 stage via permlane32_swap: a+b == row0sum + row1sum in every lane
  u32 a = __builtin_bit_cast(u32, v), b = a;
  pswap(a, b);
  return __builtin_bit_cast(float, a) + __builtin_bit_cast(float, b);
#else
  return v + __shfl_xor(v, 32, 64);
#endif
}
__device__ __forceinline__ f16x8 asf(const u32 a[4]) {
  u32x4 v; v.x = a[0]; v.y = a[1]; v.z = a[2]; v.w = a[3];
  return __builtin_bit_cast(f16x8, v);
}
__device__ __forceinline__ f16x8 ldB(const u32* p, int off) {
  u32x4 v = *(const u32x4*)(p + off);
  return __builtin_bit_cast(f16x8, v);
}

// ---- async global->LDS staging of one 8KiB matrix (2 chunks per wave,
// 4 waves cover 8 chunks). Wave-uniform LDS dest, per-lane global src;
// no destination registers consumed.
#if __has_builtin(__builtin_amdgcn_global_load_lds)
__device__ __forceinline__ void stage_mat(const u32* __restrict__ Bg,
                                          u32* lbuf, int wid, int lane) {
  #pragma unroll
  for (int c2 = 0; c2 < 2; ++c2) {
    const int c = wid * 2 + c2;
    const u32* g = Bg + c * 256 + lane * 4;
    u32* l = lbuf + c * 256;
    __builtin_amdgcn_global_load_lds(
        (const __attribute__((address_space(1))) u32*)g,
        (__attribute__((address_space(3))) u32*)l, 16, 0, 0);
  }
}
#else
__device__ __forceinline__ void stage_mat(const u32* __restrict__ Bg,
                                          u32* lbuf, int wid, int lane) {
  #pragma unroll
  for (int c2 = 0; c2 < 2; ++c2) {
    const int c = wid * 2 + c2;
    u32x4 v = *(const u32x4*)(Bg + c * 256 + lane * 4);
    *(u32x4*)(lbuf + c * 256 + lane * 4) = v;
  }
}
#endif

// fast sin/cos in revolutions (v_sin_f32/v_cos_f32 after fract reduction)
__device__ __forceinline__ void sincos_rev(float rev, float* s, float* c) {
  float r = rev - floorf(rev);
#if __has_builtin(__builtin_amdgcn_sinf) && __has_builtin(__builtin_amdgcn_cosf)
  *s = __builtin_amdgcn_sinf(r);
  *c = __builtin_amdgcn_cosf(r);
#else
  const float TWO_PI = 6.28318530717958647693f;
  sincosf(r * TWO_PI, s, c);
#endif
}

// conditional lane-xor-1 on a packed word (bfi idiom; halves have opposite
// flip conditions).
__device__ __forceinline__ u32 foldw(u32 w, u32 m) {
  u32 partner = dppx1u(w);
  return (m & partner) | (~m & w);
}

// ---------- setup: matrices (fp16, B-fragment order) from weights -----------
__global__ void setup_mats(const float* __restrict__ weights, u32* __restrict__ Bbuf) {
  const int mm = blockIdx.x >> 3;   // 0..11 ; layer = mm>>1, side: 0=P,1=Q
  const int l  = mm >> 1;
  const int qs = mm & 1;
  __shared__ float c6[6], s6[6];
  if (threadIdx.x < 6) {
    float h = 0.5f * weights[l * NQ + qs * 6 + threadIdx.x];
    c6[threadIdx.x] = cosf(h);
    s6[threadIdx.x] = sinf(h);
  }
  __syncthreads();
  const int t = (blockIdx.x & 7) * 256 + threadIdx.x;   // 0..2047
  const int lane = (t >> 2) & 63;
  const int fk   = t >> 8;          // nt*4 + kt
  const int kt   = fk & 3;
  const int nt   = fk >> 2;
  const int n     = nt * 32 + (lane & 31);
  const int kbase = kt * 16 + (lane >> 5) * 8 + (t & 3) * 2;
  float v[2];
  #pragma unroll
  for (int u = 0; u < 2; ++u) {
    int k = kbase + u;
    int bb = k;
    if (l >= 1) { bb ^= bb << 1; bb ^= bb << 2; bb ^= bb << 4; bb &= 63; } // F6
    float prod = 1.f;
    #pragma unroll
    for (int w = 0; w < 6; ++w) {
      const int aw = (n >> w) & 1, bw = (bb >> w) & 1;
      prod *= (aw == bw) ? c6[w] : (aw ? s6[w] : -s6[w]);  // RY: [[c,-s],[s,c]]
    }
    v[u] = prod;
  }
  Bbuf[mm * 2048 + t] = pkrtz(v[0], v[1]);
}

// ---------- one matmul step: repack prev D -> A frags, 16 MFMA --------------
// Bl points into LDS (ds_read_b128). Rolling 2-deep B pair (16 regs);
// MFMA cluster wrapped in s_setprio(1).
template <bool FOLD>
__device__ __forceinline__ void mm_step(f32x16 (&d)[2][2],
                                        const u32* Bl,
                                        u32 maskA, u32 maskB) {
  f16x8 Bc0 = ldB(Bl, 0 * 256);
  f16x8 Bc1 = ldB(Bl, 4 * 256);
  u32 fr[2][4][4];
  #pragma unroll
  for (int kt = 0; kt < 4; ++kt) {
    const int s  = kt >> 1;
    const int b0 = 4 * ((2 * kt) & 3);
    const int b1 = 4 * ((2 * kt + 1) & 3);
    #pragma unroll
    for (int mt = 0; mt < 2; ++mt) {
      u32 p0a = pkrtz(d[s][mt][b0 + 0], d[s][mt][b0 + 1]);
      u32 p0b = pkrtz(d[s][mt][b0 + 2], d[s][mt][b0 + 3]);
      u32 p1a = pkrtz(d[s][mt][b1 + 0], d[s][mt][b1 + 1]);
      u32 p1b = pkrtz(d[s][mt][b1 + 2], d[s][mt][b1 + 3]);
      if (FOLD) {
        const int PAR4[4] = {0, 1, 1, 0};
        const int ka = (PAR4[b0 >> 2] + s) & 1;   // low-half class of p0a
        const int kc = (PAR4[b1 >> 2] + s) & 1;   // low-half class of p1a
        p0a = foldw(p0a, ka ? maskB : maskA);
        p0b = foldw(p0b, ka ? maskA : maskB);
        p1a = foldw(p1a, kc ? maskB : maskA);
        p1b = foldw(p1b, kc ? maskA : maskB);
      }
#ifdef PSWAP_FALLBACK
      pswap_fb(p0a, p1a, false, 0);   // unreachable config on gfx950
      pswap_fb(p0b, p1b, false, 0);
#else
      pswap(p0a, p1a);
      pswap(p0b, p1b);
#endif
      fr[mt][kt][0] = p0a;
      fr[mt][kt][1] = p0b;
      fr[mt][kt][2] = p1a;
      fr[mt][kt][3] = p1b;
    }
  }
  __builtin_amdgcn_s_setprio(1);
  #pragma unroll
  for (int kt = 0; kt < 4; ++kt) {
    f16x8 B0 = Bc0, B1 = Bc1;
    if (kt < 3) {
      Bc0 = ldB(Bl, (kt + 1) * 256);       // issue next pair before MFMAs
      Bc1 = ldB(Bl, (4 + kt + 1) * 256);
    }
    f16x8 A0 = asf(fr[0][kt]);
    f16x8 A1 = asf(fr[1][kt]);
    if (kt == 0) {
      f32x16 z{};
      d[0][0] = __builtin_amdgcn_mfma_f32_32x32x16_f16(A0, B0, z, 0, 0, 0);
      d[0][1] = __builtin_amdgcn_mfma_f32_32x32x16_f16(A0, B1, z, 0, 0, 0);
      d[1][0] = __builtin_amdgcn_mfma_f32_32x32x16_f16(A1, B0, z, 0, 0, 0);
      d[1][1] = __builtin_amdgcn_mfma_f32_32x32x16_f16(A1, B1, z, 0, 0, 0);
    } else {
      d[0][0] = __builtin_amdgcn_mfma_f32_32x32x16_f16(A0, B0, d[0][0], 0, 0, 0);
      d[0][1] = __builtin_amdgcn_mfma_f32_32x32x16_f16(A0, B1, d[0][1], 0, 0, 0);
      d[1][0] = __builtin_amdgcn_mfma_f32_32x32x16_f16(A1, B0, d[1][0], 0, 0, 0);
      d[1][1] = __builtin_amdgcn_mfma_f32_32x32x16_f16(A1, B1, d[1][1], 0, 0, 0);
    }
  }
  __builtin_amdgcn_s_setprio(0);
}

__global__ void __launch_bounds__(256) __attribute__((amdgpu_waves_per_eu(3, 4)))
dqc_main(const float* __restrict__ x,
         const float* __restrict__ pre_w,
         const float* __restrict__ pre_b,
         const float* __restrict__ weights,
         const float* __restrict__ post_w,
         const float* __restrict__ post_b,
         const u32* __restrict__ Bbuf,
         float* __restrict__ out)
{
  const int lane = threadIdx.x & 63;
  const int wid  = threadIdx.x >> 6;
  const bool hi  = lane >= 32;
  const int b    = blockIdx.x * 4 + wid;
  // flip-partner masks: class k flips lower f16 when k ^ hi == 1.
  const u32 maskA = hi ? 0x0000FFFFu : 0xFFFF0000u;   // parity-class 0
  const u32 maskB = ~maskA;                            // parity-class 1

  // ---- 4-buffer rotation: stage mm2..mm5 up front (4 x 8 KiB = 32 KiB).
  __shared__ __align__(16) u32 Bs[4][2048];
  stage_mat(Bbuf + 2 * 2048, &Bs[0][0], wid, lane);   // mm2 -> buf0
  stage_mat(Bbuf + 3 * 2048, &Bs[1][0], wid, lane);   // mm3 -> buf1
  stage_mat(Bbuf + 4 * 2048, &Bs[2][0], wid, lane);   // mm4 -> buf2
  stage_mat(Bbuf + 5 * 2048, &Bs[3][0], wid, lane);   // mm5 -> buf3

  // ---- pre-GEMM: pre[w] = x[b,:] . pre_w[w,:]  (covers staging latency)
  float acc[NQ];
  const float* xr = x + (size_t)b * DIN + lane * 8;
  const float4 xa = *(const float4*)(xr);
  const float4 xb = *(const float4*)(xr + 4);
  #pragma unroll
  for (int w = 0; w < NQ; ++w) {
    const float* wr = pre_w + w * DIN + lane * 8;
    const float4 wa = *(const float4*)(wr);
    const float4 wb = *(const float4*)(wr + 4);
    acc[w] = xa.x * wa.x + xa.y * wa.y + xa.z * wa.z + xa.w * wa.w
           + xb.x * wb.x + xb.y * wb.y + xb.z * wb.z + xb.w * wb.w;
  }
  #pragma unroll
  for (int w = 0; w < NQ; ++w) acc[w] = wave_sum(acc[w]);

  // ---- u0 = cos(theta), u1 = sin(theta),
  // theta = (acc+pre_b)*pi/4 + pi/4 + 0.5*weights[0][w]  (layer-0 folded).
  const float INV_4PI = 0.07957747154594766788f;
  float u0[NQ], u1[NQ];
  #pragma unroll
  for (int w = 0; w < NQ; ++w) {
    const float cw2 = 0.125f + pre_b[w] * 0.125f + weights[w] * INV_4PI;
    const float rev = fmaf(acc[w], 0.125f, cw2);
    sincos_rev(rev, &u1[w], &u0[w]);
  }

  // ---- build MM2's A-frags directly, with layer-0's cond-flip applied:
  // element(m=q, k=p) = P(p) * Q(q ^ (par(p) & 1 on wire6)).
  float base8[8];   // wires 0-2 (j bits)
  #pragma unroll
  for (int j = 0; j < 8; ++j)
    base8[j] = ((j & 1) ? u1[0] : u0[0]) * ((j & 2) ? u1[1] : u0[1]) * ((j & 4) ? u1[2] : u0[2]);
  float hiP[4];     // wires 3(hi),4,5(kt bits)
  #pragma unroll
  for (int kt = 0; kt < 4; ++kt)
    hiP[kt] = (hi ? u1[3] : u0[3]) * ((kt & 1) ? u1[4] : u0[4]) * ((kt & 2) ? u1[5] : u0[5]);
  const float q5 = ((lane & 2) ? u1[7] : u0[7]) * ((lane & 4) ? u1[8] : u0[8])
                 * ((lane & 8) ? u1[9] : u0[9]) * ((lane & 16) ? u1[10] : u0[10]);
  const float qA = q5 * ((lane & 1) ? u1[6] : u0[6]);   // Q(q)
  const float qB = q5 * ((lane & 1) ? u0[6] : u1[6]);   // Q(q ^ wire6)
  const float qeven = hi ? qB : qA;   // class par(p)=0 (hi folded in)
  const float qodd  = hi ? qA : qB;   // class par(p)=1
  const float qe0 = qeven * u0[11], qo0 = qodd * u0[11];   // mt = 0
  const float qe1 = qeven * u1[11], qo1 = qodd * u1[11];   // mt = 1

  // all 4 prologue stages complete + visible.
  asm volatile("s_waitcnt vmcnt(0)" ::: "memory");
  __syncthreads();

  const u32* Bp0 = &Bs[0][0] + lane * 4;
  const u32* Bp1 = &Bs[1][0] + lane * 4;
  const u32* Bp2 = &Bs[2][0] + lane * 4;
  const u32* Bp3 = &Bs[3][0] + lane * 4;

  // ---- s0: init matmul (mm2) from buf0, rolling pair.
  f32x16 d[2][2];
  {
    f16x8 Ic0 = ldB(Bp0, 0 * 256);
    f16x8 Ic1 = ldB(Bp0, 4 * 256);
    const int PKT[4] = {0, 1, 1, 0};   // parity(kt)
    const int PDW[4] = {0, 1, 1, 0};   // parity(j=2*dw)
    #pragma unroll
    for (int kt = 0; kt < 4; ++kt) {
      u32 a0[4], a1[4];
      #pragma unroll
      for (int dw = 0; dw < 4; ++dw) {
        const float e0 = base8[2 * dw] * hiP[kt];
        const float e1 = base8[2 * dw + 1] * hiP[kt];
        const bool cls = (PKT[kt] ^ PDW[dw]) != 0;   // class of e0 (e1 is ^1)
        a0[dw] = pkrtz((cls ? qo0 : qe0) * e0, (cls ? qe0 : qo0) * e1);
        a1[dw] = pkrtz((cls ? qo1 : qe1) * e0, (cls ? qe1 : qo1) * e1);
      }
      f16x8 B0 = Ic0, B1 = Ic1;
      if (kt < 3) {
        Ic0 = ldB(Bp0, (kt + 1) * 256);
        Ic1 = ldB(Bp0, (4 + kt + 1) * 256);
      }
      f16x8 A0 = asf(a0), A1 = asf(a1);
      if (kt == 0) {
        f32x16 z{};
        d[0][0] = __builtin_amdgcn_mfma_f32_32x32x16_f16(A0, B0, z, 0, 0, 0);
        d[0][1] = __builtin_amdgcn_mfma_f32_32x32x16_f16(A0, B1, z, 0, 0, 0);
        d[1][0] = __builtin_amdgcn_mfma_f32_32x32x16_f16(A1, B0, z, 0, 0, 0);
        d[1][1] = __builtin_amdgcn_mfma_f32_32x32x16_f16(A1, B1, z, 0, 0, 0);
      } else {
        d[0][0] = __builtin_amdgcn_mfma_f32_32x32x16_f16(A0, B0, d[0][0], 0, 0, 0);
        d[0][1] = __builtin_amdgcn_mfma_f32_32x32x16_f16(A0, B1, d[0][1], 0, 0, 0);
        d[1][0] = __builtin_amdgcn_mfma_f32_32x32x16_f16(A1, B0, d[1][0], 0, 0, 0);
        d[1][1] = __builtin_amdgcn_mfma_f32_32x32x16_f16(A1, B1, d[1][1], 0, 0, 0);
      }
    }
  }

  // barrier every 2 steps; stage the 2 matrices for steps t+4,t+5 into the
  // buffers freed by steps t,t+1. Staged mats get 2 full steps of latency
  // cover; each __syncthreads drains this wave's vmcnt first.
  #define BAR_STAGE2(mmA, bufA, mmB, bufB)                            \
    do {                                                              \
      asm volatile("s_waitcnt vmcnt(0)" ::: "memory");                \
      __syncthreads();                                                \
      stage_mat(Bbuf + (mmA) * 2048, &Bs[bufA][0], wid, lane);        \
      stage_mat(Bbuf + (mmB) * 2048, &Bs[bufB][0], wid, lane);        \
    } while (0)

  mm_step<false>(d, Bp1, maskA, maskB);      // s1: mm3 (buf1)
  BAR_STAGE2(6, 0, 7, 1);                    // mm6->buf0, mm7->buf1
  mm_step<true >(d, Bp2, maskA, maskB);      // s2: mm4 (buf2)
  mm_step<false>(d, Bp3, maskA, maskB);      // s3: mm5 (buf3)
  BAR_STAGE2(8, 2, 9, 3);                    // mm8->buf2, mm9->buf3
  mm_step<true >(d, Bp0, maskA, maskB);      // s4: mm6 (buf0)
  mm_step<false>(d, Bp1, maskA, maskB);      // s5: mm7 (buf1)
  BAR_STAGE2(10, 0, 11, 1);                  // mm10->buf0, mm11->buf1
  mm_step<true >(d, Bp2, maskA, maskB);      // s6: mm8 (buf2)
  mm_step<false>(d, Bp3, maskA, maskB);      // s7: mm9 (buf3)
  asm volatile("s_waitcnt vmcnt(0)" ::: "memory");   // mm10/mm11 landed
  __syncthreads();
  mm_step<true >(d, Bp0, maskA, maskB);      // s8: mm10 (buf0)
  mm_step<false>(d, Bp1, maskA, maskB);      // s9: mm11 (buf1)
  #undef BAR_STAGE2

  // ---- measurement with post_w folded in (wave_sum linearity).
  const float pw0 = post_w[0], pw1 = post_w[1], pw2 = post_w[2],
              pw3 = post_w[3], pw4 = post_w[4], pw5 = post_w[5];
  float A0s = 0.f, A1s = 0.f, s00 = 0.f, s01 = 0.f, accA = 0.f, accB = 0.f;
  #pragma unroll
  for (int mt = 0; mt < 2; ++mt)
    #pragma unroll
    for (int nt = 0; nt < 2; ++nt)
      #pragma unroll
      for (int r = 0; r < 16; ++r) {
        float v = d[mt][nt][r];
        float sq = v * v;
        const int par0 = (__builtin_popcount(r & 3) + __builtin_popcount(r >> 2) + mt) & 1;
        if (par0) A1s += sq; else A0s += sq;
        if (nt == 0) { if (par0) s01 += sq; else s00 += sq; }
        const int c0 = r & 1;
        const int c1 = (r ^ (r >> 1)) & 1;
        const int c3 = c1 ^ ((r >> 2) & 1);
        const int c4 = c3 ^ ((r >> 3) & 1);
        const int c5 = c4 ^ mt;
        const float ca = (c0 ? -pw0 : pw0) + (c1 ? -pw1 : pw1);
        const float cb = (c1 ? -pw2 : pw2) + (c3 ? -pw3 : pw3)
                       + (c4 ? -pw4 : pw4) + (c5 ? -pw5 : pw5);
        accA = fmaf(ca, sq, accA);
        accB = fmaf(cb, sq, accB);
      }
  const float sgnhi = hi ? -1.f : 1.f;
  const float tot   = A0s + A1s;
  const float diff  = sgnhi * (A0s - A1s);
  const float diffs = sgnhi * (2.f * (s00 - s01) - (A0s - A1s));
  float Sq = 0.f;
  #pragma unroll
  for (int j = 0; j < 5; ++j) {
    const int par = __builtin_popcount(lane & ((2 << j) - 1)) & 1;
    Sq += par ? -post_w[6 + j] : post_w[6 + j];
  }
  const float s5 = (__builtin_popcount(lane & 31) & 1) ? -post_w[11] : post_w[11];
  const float zcomb = accA + sgnhi * accB + diff * Sq + diffs * s5;

  const float tots = wave_sum(tot);
  const float zs   = wave_sum(zcomb);

  if (lane == 0) {
    out[b] = fmaf(zs, 1.0f / tots, post_b[0]);
  }
}

extern "C" void kernel_launch(void* const* d_in, const int* in_sizes, int n_in,
                              void* d_out, int out_size, void* d_ws, size_t ws_size,
                              hipStream_t stream) {
  (void)in_sizes; (void)n_in; (void)out_size; (void)ws_size;
  const float* x       = (const float*)d_in[0];
  const float* pre_w   = (const float*)d_in[1];
  const float* pre_b   = (const float*)d_in[2];
  const float* weights = (const float*)d_in[3];
  const float* post_w  = (const float*)d_in[4];
  const float* post_b  = (const float*)d_in[5];
  float* out = (float*)d_out;
  u32* Bbuf = (u32*)d_ws;   // 12 * 2048 dwords = 96 KiB

  setup_mats<<<96, 256, 0, stream>>>(weights, Bbuf);
  dqc_main<<<BATCHN / 4, 256, 0, stream>>>(x, pre_w, pre_b, weights,
                                           post_w, post_b, Bbuf, out);
}

// Round 12
// 112.587 us; speedup vs baseline: 1.0736x; 1.0257x over previous
//
#include <hip/hip_runtime.h>
#include <math.h>

#define NQ 12
#define NL 6
#define BATCHN 8192
#define DIN 512

typedef _Float16 f16;
typedef __attribute__((ext_vector_type(8)))  _Float16 f16x8;
typedef __attribute__((ext_vector_type(16))) float    f32x16;
typedef unsigned int u32;
typedef __attribute__((ext_vector_type(4))) u32 u32x4;
typedef __attribute__((ext_vector_type(2))) int i32x2;

// ============================================================================
// 10-matmul formulation. State = 64x64 (P: wires 0-5, Q: wires 6-11).
// R24: TWO BATCH ELEMENTS PER WAVE (ILP doubling at fixed occupancy).
// Evidence ledger (R12-R23): occupancy pinned at ~2-2.5 waves/SIMD across
//   every structure (reg diets spill: R17/R20/R21; LDS/barrier variants
//   don't move residency: R16/R19/R23); per-wave ~50% idle on the serial
//   repack->MFMA->repack path; duration invariant 51-54us. R18 (51.0us,
//   global_load_lds 2x8KiB dbuf + per-step vmcnt(0)+barrier) is verified best.
// R24 keeps R18's cadence exactly and duplicates per-element state: d0,d1
//   (128 acc regs) + arch ~100 = ~230 total, inside the 2-wave bin we're
//   stuck in anyway (waves_per_eu(2,4) -> 256-reg budget, ~28 slack -- prior
//   spills were all <=128-reg budgets). The two repack/MFMA streams are
//   independent: e1's repack fills e0's MFMA-latency shadow. Barriers and
//   staging per element halve; pre_w rows load once for both elements.
// ============================================================================

__device__ __forceinline__ u32 pkrtz(float a, float b) {
  auto p = __builtin_amdgcn_cvt_pkrtz(a, b);   // __fp16 ext_vector(2)
  return __builtin_bit_cast(u32, p);
}
__device__ __forceinline__ float dppx1(float v) {  // lane xor 1 (quad_perm)
  return __int_as_float(__builtin_amdgcn_mov_dpp(__float_as_int(v), 0xB1, 0xF, 0xF, true));
}
__device__ __forceinline__ u32 dppx1u(u32 v) {
  return (u32)__builtin_amdgcn_mov_dpp((int)v, 0xB1, 0xF, 0xF, true);
}
__device__ __forceinline__ float dppx2(float v) {
  return __int_as_float(__builtin_amdgcn_mov_dpp(__float_as_int(v), 0x4E, 0xF, 0xF, true));
}
__device__ __forceinline__ float dppx8(float v) {  // row_ror:8 == xor 8
  return __int_as_float(__builtin_amdgcn_mov_dpp(__float_as_int(v), 0x128, 0xF, 0xF, true));
}
template <int PAT>
__device__ __forceinline__ float swzf(float v) {
  return __int_as_float(__builtin_amdgcn_ds_swizzle(__float_as_int(v), PAT));
}

// half-swap across the lane-32 boundary.
#if __has_builtin(__builtin_amdgcn_permlane32_swap)
__device__ __forceinline__ void pswap(u32& a, u32& b) {
  i32x2 r = __builtin_amdgcn_permlane32_swap((int)a, (int)b, false, false);
  a = (u32)r.x; b = (u32)r.y;
}
#else
#define PSWAP_FALLBACK 1
__device__ __forceinline__ void pswap_fb(u32& a, u32& b, bool hi, int axor) {
  u32 xa = (u32)__builtin_amdgcn_ds_bpermute(axor, (int)a);
  u32 xb = (u32)__builtin_amdgcn_ds_bpermute(axor, (int)b);
  u32 na = hi ? xb : a;
  u32 nb = hi ? b : xa;
  a = na; b = nb;
}
#endif

__device__ __forceinline__ float wave_sum(float v) {
  v += dppx1(v);
  v += dppx2(v);
  v += swzf<0x101F>(v);   // xor 4
  v += dppx8(v);
  v += swzf<0x401F>(v);   // xor 16
#ifndef PSWAP_FALLBACK
  u32 a = __builtin_bit_cast(u32, v), b = a;
  pswap(a, b);
  return __builtin_bit_cast(float, a) + __builtin_bit_cast(float, b);
#else
  return v + __shfl_xor(v, 32, 64);
#endif
}
__device__ __forceinline__ f16x8 asf(const u32 a[4]) {
  u32x4 v; v.x = a[0]; v.y = a[1]; v.z = a[2]; v.w = a[3];
  return __builtin_bit_cast(f16x8, v);
}
__device__ __forceinline__ f16x8 ldB(const u32* p, int off) {
  u32x4 v = *(const u32x4*)(p + off);
  return __builtin_bit_cast(f16x8, v);
}

// ---- async global->LDS staging of one 8KiB matrix (2 chunks per wave,
// 4 waves cover 8 chunks). No destination registers consumed.
#if __has_builtin(__builtin_amdgcn_global_load_lds)
__device__ __forceinline__ void stage_mat(const u32* __restrict__ Bg,
                                          u32* lbuf, int wid, int lane) {
  #pragma unroll
  for (int c2 = 0; c2 < 2; ++c2) {
    const int c = wid * 2 + c2;
    const u32* g = Bg + c * 256 + lane * 4;
    u32* l = lbuf + c * 256;
    __builtin_amdgcn_global_load_lds(
        (const __attribute__((address_space(1))) u32*)g,
        (__attribute__((address_space(3))) u32*)l, 16, 0, 0);
  }
}
#else
__device__ __forceinline__ void stage_mat(const u32* __restrict__ Bg,
                                          u32* lbuf, int wid, int lane) {
  #pragma unroll
  for (int c2 = 0; c2 < 2; ++c2) {
    const int c = wid * 2 + c2;
    u32x4 v = *(const u32x4*)(Bg + c * 256 + lane * 4);
    *(u32x4*)(lbuf + c * 256 + lane * 4) = v;
  }
}
#endif

// fast sin/cos in revolutions (v_sin_f32/v_cos_f32 after fract reduction)
__device__ __forceinline__ void sincos_rev(float rev, float* s, float* c) {
  float r = rev - floorf(rev);
#if __has_builtin(__builtin_amdgcn_sinf) && __has_builtin(__builtin_amdgcn_cosf)
  *s = __builtin_amdgcn_sinf(r);
  *c = __builtin_amdgcn_cosf(r);
#else
  const float TWO_PI = 6.28318530717958647693f;
  sincosf(r * TWO_PI, s, c);
#endif
}

// conditional lane-xor-1 on a packed word (bfi idiom)
__device__ __forceinline__ u32 foldw(u32 w, u32 m) {
  u32 partner = dppx1u(w);
  return (m & partner) | (~m & w);
}

// ---------- setup: matrices (fp16, B-fragment order) from weights -----------
__global__ void setup_mats(const float* __restrict__ weights, u32* __restrict__ Bbuf) {
  const int mm = blockIdx.x >> 3;   // 0..11 ; layer = mm>>1, side: 0=P,1=Q
  const int l  = mm >> 1;
  const int qs = mm & 1;
  __shared__ float c6[6], s6[6];
  if (threadIdx.x < 6) {
    float h = 0.5f * weights[l * NQ + qs * 6 + threadIdx.x];
    c6[threadIdx.x] = cosf(h);
    s6[threadIdx.x] = sinf(h);
  }
  __syncthreads();
  const int t = (blockIdx.x & 7) * 256 + threadIdx.x;   // 0..2047
  const int lane = (t >> 2) & 63;
  const int fk   = t >> 8;          // nt*4 + kt
  const int kt   = fk & 3;
  const int nt   = fk >> 2;
  const int n     = nt * 32 + (lane & 31);
  const int kbase = kt * 16 + (lane >> 5) * 8 + (t & 3) * 2;
  float v[2];
  #pragma unroll
  for (int u = 0; u < 2; ++u) {
    int k = kbase + u;
    int bb = k;
    if (l >= 1) { bb ^= bb << 1; bb ^= bb << 2; bb ^= bb << 4; bb &= 63; } // F6
    float prod = 1.f;
    #pragma unroll
    for (int w = 0; w < 6; ++w) {
      const int aw = (n >> w) & 1, bw = (bb >> w) & 1;
      prod *= (aw == bw) ? c6[w] : (aw ? s6[w] : -s6[w]);  // RY: [[c,-s],[s,c]]
    }
    v[u] = prod;
  }
  Bbuf[mm * 2048 + t] = pkrtz(v[0], v[1]);
}

// ---------- one matmul step for ONE element (verbatim R18 structure) --------
template <bool FOLD>
__device__ __forceinline__ void mm_one(f32x16 (&d)[2][2],
                                       const u32* Bl,
                                       u32 maskA, u32 maskB) {
  f16x8 Bc0 = ldB(Bl, 0 * 256);
  f16x8 Bc1 = ldB(Bl, 4 * 256);
  u32 fr[2][4][4];
  #pragma unroll
  for (int kt = 0; kt < 4; ++kt) {
    const int s  = kt >> 1;
    const int b0 = 4 * ((2 * kt) & 3);
    const int b1 = 4 * ((2 * kt + 1) & 3);
    #pragma unroll
    for (int mt = 0; mt < 2; ++mt) {
      u32 p0a = pkrtz(d[s][mt][b0 + 0], d[s][mt][b0 + 1]);
      u32 p0b = pkrtz(d[s][mt][b0 + 2], d[s][mt][b0 + 3]);
      u32 p1a = pkrtz(d[s][mt][b1 + 0], d[s][mt][b1 + 1]);
      u32 p1b = pkrtz(d[s][mt][b1 + 2], d[s][mt][b1 + 3]);
      if (FOLD) {
        const int PAR4[4] = {0, 1, 1, 0};
        const int ka = (PAR4[b0 >> 2] + s) & 1;   // low-half class of p0a
        const int kc = (PAR4[b1 >> 2] + s) & 1;   // low-half class of p1a
        p0a = foldw(p0a, ka ? maskB : maskA);
        p0b = foldw(p0b, ka ? maskA : maskB);
        p1a = foldw(p1a, kc ? maskB : maskA);
        p1b = foldw(p1b, kc ? maskA : maskB);
      }
#ifdef PSWAP_FALLBACK
      pswap_fb(p0a, p1a, false, 0);   // unreachable config on gfx950
      pswap_fb(p0b, p1b, false, 0);
#else
      pswap(p0a, p1a);
      pswap(p0b, p1b);
#endif
      fr[mt][kt][0] = p0a;
      fr[mt][kt][1] = p0b;
      fr[mt][kt][2] = p1a;
      fr[mt][kt][3] = p1b;
    }
  }
  #pragma unroll
  for (int kt = 0; kt < 4; ++kt) {
    f16x8 B0 = Bc0, B1 = Bc1;
    if (kt < 3) {
      Bc0 = ldB(Bl, (kt + 1) * 256);       // issue next pair before MFMAs
      Bc1 = ldB(Bl, (4 + kt + 1) * 256);
    }
    f16x8 A0 = asf(fr[0][kt]);
    f16x8 A1 = asf(fr[1][kt]);
    if (kt == 0) {
      f32x16 z{};
      d[0][0] = __builtin_amdgcn_mfma_f32_32x32x16_f16(A0, B0, z, 0, 0, 0);
      d[0][1] = __builtin_amdgcn_mfma_f32_32x32x16_f16(A0, B1, z, 0, 0, 0);
      d[1][0] = __builtin_amdgcn_mfma_f32_32x32x16_f16(A1, B0, z, 0, 0, 0);
      d[1][1] = __builtin_amdgcn_mfma_f32_32x32x16_f16(A1, B1, z, 0, 0, 0);
    } else {
      d[0][0] = __builtin_amdgcn_mfma_f32_32x32x16_f16(A0, B0, d[0][0], 0, 0, 0);
      d[0][1] = __builtin_amdgcn_mfma_f32_32x32x16_f16(A0, B1, d[0][1], 0, 0, 0);
      d[1][0] = __builtin_amdgcn_mfma_f32_32x32x16_f16(A1, B0, d[1][0], 0, 0, 0);
      d[1][1] = __builtin_amdgcn_mfma_f32_32x32x16_f16(A1, B1, d[1][1], 0, 0, 0);
    }
  }
}

// ---------- build init scalars for one element (consumes its trig set) ------
__device__ __forceinline__ void build_scal(const float (&acc)[NQ],
    const float* __restrict__ pre_b, const float* __restrict__ weights,
    int lane, bool hi,
    float (&base8)[8], float (&hiP)[4],
    float& qe0, float& qo0, float& qe1, float& qo1) {
  const float INV_4PI = 0.07957747154594766788f;
  float u0[NQ], u1[NQ];
  #pragma unroll
  for (int w = 0; w < NQ; ++w) {
    const float cw2 = 0.125f + pre_b[w] * 0.125f + weights[w] * INV_4PI;
    const float rev = fmaf(acc[w], 0.125f, cw2);
    sincos_rev(rev, &u1[w], &u0[w]);
  }
  #pragma unroll
  for (int j = 0; j < 8; ++j)
    base8[j] = ((j & 1) ? u1[0] : u0[0]) * ((j & 2) ? u1[1] : u0[1]) * ((j & 4) ? u1[2] : u0[2]);
  #pragma unroll
  for (int kt = 0; kt < 4; ++kt)
    hiP[kt] = (hi ? u1[3] : u0[3]) * ((kt & 1) ? u1[4] : u0[4]) * ((kt & 2) ? u1[5] : u0[5]);
  const float q5 = ((lane & 2) ? u1[7] : u0[7]) * ((lane & 4) ? u1[8] : u0[8])
                 * ((lane & 8) ? u1[9] : u0[9]) * ((lane & 16) ? u1[10] : u0[10]);
  const float qA = q5 * ((lane & 1) ? u1[6] : u0[6]);   // Q(q)
  const float qB = q5 * ((lane & 1) ? u0[6] : u1[6]);   // Q(q ^ wire6)
  const float qeven = hi ? qB : qA;   // class par(p)=0 (hi folded in)
  const float qodd  = hi ? qA : qB;   // class par(p)=1
  qe0 = qeven * u0[11]; qo0 = qodd * u0[11];   // mt = 0
  qe1 = qeven * u1[11]; qo1 = qodd * u1[11];   // mt = 1
}

// ---------- init matmul (mm2) for one element (verbatim R18 structure) ------
__device__ __forceinline__ void init_mm2(f32x16 (&d)[2][2], const u32* Bp0,
    const float (&base8)[8], const float (&hiP)[4],
    float qe0, float qo0, float qe1, float qo1) {
  f16x8 Ic0 = ldB(Bp0, 0 * 256);
  f16x8 Ic1 = ldB(Bp0, 4 * 256);
  const int PKT[4] = {0, 1, 1, 0};   // parity(kt)
  const int PDW[4] = {0, 1, 1, 0};   // parity(j=2*dw)
  #pragma unroll
  for (int kt = 0; kt < 4; ++kt) {
    u32 a0[4], a1[4];
    #pragma unroll
    for (int dw = 0; dw < 4; ++dw) {
      const float e0 = base8[2 * dw] * hiP[kt];
      const float e1 = base8[2 * dw + 1] * hiP[kt];
      const bool cls = (PKT[kt] ^ PDW[dw]) != 0;   // class of e0 (e1 is ^1)
      a0[dw] = pkrtz((cls ? qo0 : qe0) * e0, (cls ? qe0 : qo0) * e1);
      a1[dw] = pkrtz((cls ? qo1 : qe1) * e0, (cls ? qe1 : qo1) * e1);
    }
    f16x8 B0 = Ic0, B1 = Ic1;
    if (kt < 3) {
      Ic0 = ldB(Bp0, (kt + 1) * 256);
      Ic1 = ldB(Bp0, (4 + kt + 1) * 256);
    }
    f16x8 A0 = asf(a0), A1 = asf(a1);
    if (kt == 0) {
      f32x16 z{};
      d[0][0] = __builtin_amdgcn_mfma_f32_32x32x16_f16(A0, B0, z, 0, 0, 0);
      d[0][1] = __builtin_amdgcn_mfma_f32_32x32x16_f16(A0, B1, z, 0, 0, 0);
      d[1][0] = __builtin_amdgcn_mfma_f32_32x32x16_f16(A1, B0, z, 0, 0, 0);
      d[1][1] = __builtin_amdgcn_mfma_f32_32x32x16_f16(A1, B1, z, 0, 0, 0);
    } else {
      d[0][0] = __builtin_amdgcn_mfma_f32_32x32x16_f16(A0, B0, d[0][0], 0, 0, 0);
      d[0][1] = __builtin_amdgcn_mfma_f32_32x32x16_f16(A0, B1, d[0][1], 0, 0, 0);
      d[1][0] = __builtin_amdgcn_mfma_f32_32x32x16_f16(A1, B0, d[1][0], 0, 0, 0);
      d[1][1] = __builtin_amdgcn_mfma_f32_32x32x16_f16(A1, B1, d[1][1], 0, 0, 0);
    }
  }
}

// ---------- measurement for one element (verbatim R18 epilogue) -------------
__device__ __forceinline__ void measure(const f32x16 (&d)[2][2], int b,
    int lane, bool hi,
    const float* __restrict__ post_w, const float* __restrict__ post_b,
    float* __restrict__ out) {
  const float pw0 = post_w[0], pw1 = post_w[1], pw2 = post_w[2],
              pw3 = post_w[3], pw4 = post_w[4], pw5 = post_w[5];
  float A0s = 0.f, A1s = 0.f, s00 = 0.f, s01 = 0.f, accA = 0.f, accB = 0.f;
  #pragma unroll
  for (int mt = 0; mt < 2; ++mt)
    #pragma unroll
    for (int nt = 0; nt < 2; ++nt)
      #pragma unroll
      for (int r = 0; r < 16; ++r) {
        float v = d[mt][nt][r];
        float sq = v * v;
        const int par0 = (__builtin_popcount(r & 3) + __builtin_popcount(r >> 2) + mt) & 1;
        if (par0) A1s += sq; else A0s += sq;
        if (nt == 0) { if (par0) s01 += sq; else s00 += sq; }
        const int c0 = r & 1;
        const int c1 = (r ^ (r >> 1)) & 1;
        const int c3 = c1 ^ ((r >> 2) & 1);
        const int c4 = c3 ^ ((r >> 3) & 1);
        const int c5 = c4 ^ mt;
        const float ca = (c0 ? -pw0 : pw0) + (c1 ? -pw1 : pw1);
        const float cb = (c1 ? -pw2 : pw2) + (c3 ? -pw3 : pw3)
                       + (c4 ? -pw4 : pw4) + (c5 ? -pw5 : pw5);
        accA = fmaf(ca, sq, accA);
        accB = fmaf(cb, sq, accB);
      }
  const float sgnhi = hi ? -1.f : 1.f;
  const float tot   = A0s + A1s;
  const float diff  = sgnhi * (A0s - A1s);
  const float diffs = sgnhi * (2.f * (s00 - s01) - (A0s - A1s));
  float Sq = 0.f;
  #pragma unroll
  for (int j = 0; j < 5; ++j) {
    const int par = __builtin_popcount(lane & ((2 << j) - 1)) & 1;
    Sq += par ? -post_w[6 + j] : post_w[6 + j];
  }
  const float s5 = (__builtin_popcount(lane & 31) & 1) ? -post_w[11] : post_w[11];
  const float zcomb = accA + sgnhi * accB + diff * Sq + diffs * s5;

  const float tots = wave_sum(tot);
  const float zs   = wave_sum(zcomb);

  if (lane == 0) {
    out[b] = fmaf(zs, 1.0f / tots, post_b[0]);
  }
}

__global__ void __launch_bounds__(256) __attribute__((amdgpu_waves_per_eu(2, 4)))
dqc_main(const float* __restrict__ x,
         const float* __restrict__ pre_w,
         const float* __restrict__ pre_b,
         const float* __restrict__ weights,
         const float* __restrict__ post_w,
         const float* __restrict__ post_b,
         const u32* __restrict__ Bbuf,
         float* __restrict__ out)
{
  const int lane = threadIdx.x & 63;
  const int wid  = threadIdx.x >> 6;
  const bool hi  = lane >= 32;
  const int b0   = blockIdx.x * 8 + wid * 2;   // two elements per wave
  const int b1   = b0 + 1;
  const u32 maskA = hi ? 0x0000FFFFu : 0xFFFF0000u;   // parity-class 0
  const u32 maskB = ~maskA;                            // parity-class 1

  // ---- double-buffered B staging: 2 x 8 KiB. mm even -> Bs[0], odd -> Bs[1].
  __shared__ __align__(16) u32 Bs[2][2048];
  stage_mat(Bbuf + 2 * 2048, &Bs[0][0], wid, lane);   // mm2 -> buf0
  stage_mat(Bbuf + 3 * 2048, &Bs[1][0], wid, lane);   // mm3 -> buf1

  // ---- pre-GEMM for BOTH elements (pre_w rows loaded once; covers staging)
  float acc0[NQ], acc1[NQ];
  const float* xr0 = x + (size_t)b0 * DIN + lane * 8;
  const float* xr1 = x + (size_t)b1 * DIN + lane * 8;
  const float4 xa0 = *(const float4*)(xr0);
  const float4 xb0 = *(const float4*)(xr0 + 4);
  const float4 xa1 = *(const float4*)(xr1);
  const float4 xb1 = *(const float4*)(xr1 + 4);
  #pragma unroll
  for (int w = 0; w < NQ; ++w) {
    const float* wr = pre_w + w * DIN + lane * 8;
    const float4 wa = *(const float4*)(wr);
    const float4 wb = *(const float4*)(wr + 4);
    acc0[w] = xa0.x * wa.x + xa0.y * wa.y + xa0.z * wa.z + xa0.w * wa.w
            + xb0.x * wb.x + xb0.y * wb.y + xb0.z * wb.z + xb0.w * wb.w;
    acc1[w] = xa1.x * wa.x + xa1.y * wa.y + xa1.z * wa.z + xa1.w * wa.w
            + xb1.x * wb.x + xb1.y * wb.y + xb1.z * wb.z + xb1.w * wb.w;
  }
  #pragma unroll
  for (int w = 0; w < NQ; ++w) acc0[w] = wave_sum(acc0[w]);
  #pragma unroll
  for (int w = 0; w < NQ; ++w) acc1[w] = wave_sum(acc1[w]);

  // ---- init scalars per element (trig set freed after each build)
  float b8A[8], hPA[4], qe0A, qo0A, qe1A, qo1A;
  build_scal(acc0, pre_b, weights, lane, hi, b8A, hPA, qe0A, qo0A, qe1A, qo1A);
  float b8B[8], hPB[4], qe0B, qo0B, qe1B, qo1B;
  build_scal(acc1, pre_b, weights, lane, hi, b8B, hPB, qe0B, qo0B, qe1B, qo1B);

  // staging complete + visible before first use.
  asm volatile("s_waitcnt vmcnt(0)" ::: "memory");
  __syncthreads();

  const u32* B0p = &Bs[0][0] + lane * 4;
  const u32* B1p = &Bs[1][0] + lane * 4;

  // ---- s0: init matmul (mm2) for both elements from buf0.
  f32x16 d0[2][2], d1[2][2];
  init_mm2(d0, B0p, b8A, hPA, qe0A, qo0A, qe1A, qo1A);
  init_mm2(d1, B0p, b8B, hPB, qe0B, qo0B, qe1B, qo1B);

  // ---- step tail: wait prev prefetch, sync, issue prefetch of mat `nextmm`
  // into the buffer just freed by this step (R18 cadence, verbatim).
  #define STEP_TAIL(nextmm, bufidx)                                  \
    do {                                                             \
      asm volatile("s_waitcnt vmcnt(0)" ::: "memory");               \
      __syncthreads();                                               \
      stage_mat(Bbuf + (nextmm) * 2048, &Bs[bufidx][0], wid, lane);  \
    } while (0)

  STEP_TAIL(4, 0);                              // end s0: mm4 -> buf0
  mm_one<false>(d0, B1p, maskA, maskB);         // s1: mm3 (buf1)
  mm_one<false>(d1, B1p, maskA, maskB);
  STEP_TAIL(5, 1);                              // mm5 -> buf1
  mm_one<true >(d0, B0p, maskA, maskB);         // s2: mm4 (buf0)
  mm_one<true >(d1, B0p, maskA, maskB);
  STEP_TAIL(6, 0);                              // mm6 -> buf0
  mm_one<false>(d0, B1p, maskA, maskB);         // s3: mm5 (buf1)
  mm_one<false>(d1, B1p, maskA, maskB);
  STEP_TAIL(7, 1);                              // mm7 -> buf1
  mm_one<true >(d0, B0p, maskA, maskB);         // s4: mm6 (buf0)
  mm_one<true >(d1, B0p, maskA, maskB);
  STEP_TAIL(8, 0);                              // mm8 -> buf0
  mm_one<false>(d0, B1p, maskA, maskB);         // s5: mm7 (buf1)
  mm_one<false>(d1, B1p, maskA, maskB);
  STEP_TAIL(9, 1);                              // mm9 -> buf1
  mm_one<true >(d0, B0p, maskA, maskB);         // s6: mm8 (buf0)
  mm_one<true >(d1, B0p, maskA, maskB);
  STEP_TAIL(10, 0);                             // mm10 -> buf0
  mm_one<false>(d0, B1p, maskA, maskB);         // s7: mm9 (buf1)
  mm_one<false>(d1, B1p, maskA, maskB);
  STEP_TAIL(11, 1);                             // mm11 -> buf1
  mm_one<true >(d0, B0p, maskA, maskB);         // s8: mm10 (buf0)
  mm_one<true >(d1, B0p, maskA, maskB);
  asm volatile("s_waitcnt vmcnt(0)" ::: "memory");   // mm11 landed
  __syncthreads();
  mm_one<false>(d0, B1p, maskA, maskB);         // s9: mm11 (buf1)
  mm_one<false>(d1, B1p, maskA, maskB);
  #undef STEP_TAIL

  // ---- measurement for both elements.
  measure(d0, b0, lane, hi, post_w, post_b, out);
  measure(d1, b1, lane, hi, post_w, post_b, out);
}

extern "C" void kernel_launch(void* const* d_in, const int* in_sizes, int n_in,
                              void* d_out, int out_size, void* d_ws, size_t ws_size,
                              hipStream_t stream) {
  (void)in_sizes; (void)n_in; (void)out_size; (void)ws_size;
  const float* x       = (const float*)d_in[0];
  const float* pre_w   = (const float*)d_in[1];
  const float* pre_b   = (const float*)d_in[2];
  const float* weights = (const float*)d_in[3];
  const float* post_w  = (const float*)d_in[4];
  const float* post_b  = (const float*)d_in[5];
  float* out = (float*)d_out;
  u32* Bbuf = (u32*)d_ws;   // 12 * 2048 dwords = 96 KiB

  setup_mats<<<96, 256, 0, stream>>>(weights, Bbuf);
  dqc_main<<<BATCHN / 8, 256, 0, stream>>>(x, pre_w, pre_b, weights,
                                           post_w, post_b, Bbuf, out);
}